// Round 1
// baseline (1008.213 us; speedup 1.0000x reference)
//
#include <hip/hip_runtime.h>
#include <hip/hip_bf16.h>
#include <math.h>

#define EMB 128
#define OUT 256
#define RAD 6
#define NDL 3
#define NTGT 12
#define NT 32   // nodes per chain block

// ---------------- CSR build ----------------

__global__ void hist_kernel(const int* __restrict__ src, int* __restrict__ counts, int E) {
    int i = blockIdx.x * blockDim.x + threadIdx.x;
    if (i < E) atomicAdd(&counts[src[i]], 1);
}

__global__ void scan_kernel(const int* __restrict__ counts, int* __restrict__ offs,
                            int* __restrict__ cursor, int N) {
    __shared__ int sums[1024];
    int tid = threadIdx.x;
    int chunk = (N + 1023) / 1024;
    int beg = tid * chunk;
    int end = min(beg + chunk, N);
    int s = 0;
    for (int i = beg; i < end; i++) s += counts[i];
    int mysum = s;
    sums[tid] = s;
    __syncthreads();
    // Hillis-Steele inclusive scan over 1024 chunk sums
    for (int off = 1; off < 1024; off <<= 1) {
        int add = (tid >= off) ? sums[tid - off] : 0;
        __syncthreads();
        sums[tid] += add;
        __syncthreads();
    }
    int prefix = sums[tid] - mysum;  // exclusive start of my chunk
    for (int i = beg; i < end; i++) {
        int c = counts[i];
        offs[i] = prefix;
        cursor[i] = prefix;
        prefix += c;
    }
    if (tid == 0) offs[N] = sums[1023];
}

__global__ void scatter_kernel(const int* __restrict__ src, int* __restrict__ cursor,
                               int* __restrict__ eids, int E) {
    int i = blockIdx.x * blockDim.x + threadIdx.x;
    if (i < E) {
        int pos = atomicAdd(&cursor[src[i]], 1);
        eids[pos] = i;
    }
}

// ---------------- edge gather: t0[n,:] = sum_e m[e,:] * (rbf[e,:] @ w_rbf) ----------------

__global__ void gather_kernel(const float* __restrict__ m, const float* __restrict__ rbf,
                              const float* __restrict__ w_rbf,
                              const int* __restrict__ offs, const int* __restrict__ eids,
                              float* __restrict__ t0, int N) {
    int n = blockIdx.x;
    int tid = threadIdx.x;  // 128 threads, one per emb element
    float wr[RAD];
#pragma unroll
    for (int r = 0; r < RAD; r++) wr[r] = w_rbf[r * EMB + tid];

    int b = offs[n], e = offs[n + 1];
    float acc = 0.f;
    int idx = b;
    for (; idx + 2 <= e; idx += 2) {
        int e0 = eids[idx], e1 = eids[idx + 1];
        float c0 = 0.f, c1 = 0.f;
#pragma unroll
        for (int r = 0; r < RAD; r++) {
            c0 += rbf[(size_t)e0 * RAD + r] * wr[r];
            c1 += rbf[(size_t)e1 * RAD + r] * wr[r];
        }
        float m0 = m[(size_t)e0 * EMB + tid];
        float m1 = m[(size_t)e1 * EMB + tid];
        acc += m0 * c0;
        acc += m1 * c1;
    }
    if (idx < e) {
        int e0 = eids[idx];
        float c0 = 0.f;
#pragma unroll
        for (int r = 0; r < RAD; r++) c0 += rbf[(size_t)e0 * RAD + r] * wr[r];
        acc += m[(size_t)e0 * EMB + tid] * c0;
    }
    t0[(size_t)n * EMB + tid] = acc;
}

// ---------------- node MLP chain + per-graph reduce ----------------
// 256 threads = 128 col-threads (c) x 2 node-groups (g). Each thread: 16 nodes x 2 cols.

__global__ __launch_bounds__(256) void chain_kernel(
    const float* __restrict__ t0, const float* __restrict__ w_up,
    const float* __restrict__ w_dense, const float* __restrict__ b_dense,
    const float* __restrict__ w_final, const int* __restrict__ node2graph,
    float* __restrict__ out, int N) {
    __shared__ float sIn[NT * EMB];    // 16 KB
    __shared__ float sAct[NT * OUT];   // 32 KB
    int tid = threadIdx.x;
    int n0 = blockIdx.x * NT;
    int c = tid & 127;      // column thread
    int g = tid >> 7;       // node group (wave-uniform: waves 0,1 -> g=0; 2,3 -> g=1)

    // stage input tile (rows are contiguous in t0)
    {
        int base = n0 * EMB;
        int lim = N * EMB;
        for (int i = tid; i < NT * EMB; i += 256) {
            int gi = base + i;
            sIn[i] = (gi < lim) ? t0[gi] : 0.f;
        }
    }
    __syncthreads();

    float acc[16][2];

    // ---- up projection: K=128 -> 256, no bias/act ----
#pragma unroll
    for (int i = 0; i < 16; i++) { acc[i][0] = 0.f; acc[i][1] = 0.f; }
    for (int k = 0; k < EMB; k += 4) {
        float w0[4], w1[4];
#pragma unroll
        for (int kk = 0; kk < 4; kk++) {
            w0[kk] = w_up[(k + kk) * OUT + c];
            w1[kk] = w_up[(k + kk) * OUT + c + 128];
        }
#pragma unroll
        for (int i = 0; i < 16; i++) {
            float4 a = *(const float4*)&sIn[(g * 16 + i) * EMB + k];
            acc[i][0] += a.x * w0[0] + a.y * w0[1] + a.z * w0[2] + a.w * w0[3];
            acc[i][1] += a.x * w1[0] + a.y * w1[1] + a.z * w1[2] + a.w * w1[3];
        }
    }
#pragma unroll
    for (int i = 0; i < 16; i++) {
        sAct[(g * 16 + i) * OUT + c] = acc[i][0];
        sAct[(g * 16 + i) * OUT + c + 128] = acc[i][1];
    }
    __syncthreads();

    // ---- 3 dense layers 256->256 with silu ----
    for (int l = 0; l < NDL; l++) {
        const float* W = w_dense + (size_t)l * OUT * OUT;
#pragma unroll
        for (int i = 0; i < 16; i++) { acc[i][0] = 0.f; acc[i][1] = 0.f; }
        for (int k = 0; k < OUT; k += 4) {
            float w0[4], w1[4];
#pragma unroll
            for (int kk = 0; kk < 4; kk++) {
                w0[kk] = W[(k + kk) * OUT + c];
                w1[kk] = W[(k + kk) * OUT + c + 128];
            }
#pragma unroll
            for (int i = 0; i < 16; i++) {
                float4 a = *(const float4*)&sAct[(g * 16 + i) * OUT + k];
                acc[i][0] += a.x * w0[0] + a.y * w0[1] + a.z * w0[2] + a.w * w0[3];
                acc[i][1] += a.x * w1[0] + a.y * w1[1] + a.z * w1[2] + a.w * w1[3];
            }
        }
        __syncthreads();  // all reads of sAct done before overwrite
        float b0 = b_dense[l * OUT + c];
        float b1 = b_dense[l * OUT + c + 128];
#pragma unroll
        for (int i = 0; i < 16; i++) {
            float x0 = acc[i][0] + b0;
            float x1 = acc[i][1] + b1;
            sAct[(g * 16 + i) * OUT + c]       = x0 / (1.f + __expf(-x0));
            sAct[(g * 16 + i) * OUT + c + 128] = x1 / (1.f + __expf(-x1));
        }
        __syncthreads();
    }

    // ---- final 256 -> 12 + per-graph atomic reduce ----
    for (int p = tid; p < NT * NTGT; p += 256) {
        int n = p / NTGT;
        int t = p % NTGT;
        int node = n0 + n;
        if (node < N) {
            float s = 0.f;
            for (int k = 0; k < OUT; k += 4) {
                float4 a = *(const float4*)&sAct[n * OUT + k];
                s += a.x * w_final[(k + 0) * NTGT + t];
                s += a.y * w_final[(k + 1) * NTGT + t];
                s += a.z * w_final[(k + 2) * NTGT + t];
                s += a.w * w_final[(k + 3) * NTGT + t];
            }
            atomicAdd(&out[node2graph[node] * NTGT + t], s);
        }
    }
}

// ---------------- launch ----------------

extern "C" void kernel_launch(void* const* d_in, const int* in_sizes, int n_in,
                              void* d_out, int out_size, void* d_ws, size_t ws_size,
                              hipStream_t stream) {
    const float* m        = (const float*)d_in[0];
    const float* rbf      = (const float*)d_in[1];
    const int*   edge_src = (const int*)d_in[2];
    const int*   node2g   = (const int*)d_in[3];
    const float* w_rbf    = (const float*)d_in[4];
    const float* w_up     = (const float*)d_in[5];
    const float* w_dense  = (const float*)d_in[6];
    const float* b_dense  = (const float*)d_in[7];
    const float* w_final  = (const float*)d_in[8];

    int E = in_sizes[2];
    int N = in_sizes[3];
    float* out = (float*)d_out;

    char* p = (char*)d_ws;
    auto alloc = [&](size_t bytes) {
        char* r = p;
        p += (bytes + 255) & ~(size_t)255;
        return r;
    };
    int*   counts = (int*)alloc((size_t)N * 4);
    int*   offs   = (int*)alloc((size_t)(N + 1) * 4);
    int*   cursor = (int*)alloc((size_t)N * 4);
    int*   eids   = (int*)alloc((size_t)E * 4);
    float* t0     = (float*)alloc((size_t)N * EMB * 4);

    hipMemsetAsync(counts, 0, (size_t)N * 4, stream);
    hipMemsetAsync(d_out, 0, (size_t)out_size * 4, stream);

    hist_kernel<<<(E + 255) / 256, 256, 0, stream>>>(edge_src, counts, E);
    scan_kernel<<<1, 1024, 0, stream>>>(counts, offs, cursor, N);
    scatter_kernel<<<(E + 255) / 256, 256, 0, stream>>>(edge_src, cursor, eids, E);
    gather_kernel<<<N, EMB, 0, stream>>>(m, rbf, w_rbf, offs, eids, t0, N);
    chain_kernel<<<(N + NT - 1) / NT, 256, 0, stream>>>(t0, w_up, w_dense, b_dense,
                                                        w_final, node2g, out, N);
}

// Round 2
// 773.807 us; speedup vs baseline: 1.3029x; 1.3029x over previous
//
#include <hip/hip_runtime.h>
#include <hip/hip_bf16.h>
#include <math.h>

#define EMB 128
#define OUT 256
#define RAD 6
#define NDL 3
#define NTGT 12
#define MT 32          // nodes per chain block
#define S 264          // LDS activation stride (bf16 elems): 264*2=528B, 16B-aligned rows, good bank spread

typedef __attribute__((ext_vector_type(8))) short short8;
typedef __attribute__((ext_vector_type(4))) float floatx4;

__device__ inline short f2bf(float x) {
    __hip_bfloat16 h = __float2bfloat16(x);
    return *reinterpret_cast<short*>(&h);
}

// ---------------- CSR build ----------------

__global__ void hist_kernel(const int* __restrict__ src, int* __restrict__ counts, int E) {
    int i = blockIdx.x * blockDim.x + threadIdx.x;
    if (i < E) atomicAdd(&counts[src[i]], 1);
}

__global__ void scan_kernel(const int* __restrict__ counts, int* __restrict__ offs,
                            int* __restrict__ cursor, int N) {
    __shared__ int sums[1024];
    int tid = threadIdx.x;
    int chunk = (N + 1023) / 1024;
    int beg = tid * chunk;
    int end = min(beg + chunk, N);
    int s = 0;
    for (int i = beg; i < end; i++) s += counts[i];
    int mysum = s;
    sums[tid] = s;
    __syncthreads();
    for (int off = 1; off < 1024; off <<= 1) {
        int add = (tid >= off) ? sums[tid - off] : 0;
        __syncthreads();
        sums[tid] += add;
        __syncthreads();
    }
    int prefix = sums[tid] - mysum;
    for (int i = beg; i < end; i++) {
        int c = counts[i];
        offs[i] = prefix;
        cursor[i] = prefix;
        prefix += c;
    }
    if (tid == 0) offs[N] = sums[1023];
}

__global__ void scatter_kernel(const int* __restrict__ src, int* __restrict__ cursor,
                               int* __restrict__ eids, int E) {
    int i = blockIdx.x * blockDim.x + threadIdx.x;
    if (i < E) {
        int pos = atomicAdd(&cursor[src[i]], 1);
        eids[pos] = i;
    }
}

// ---------------- weight prep: bf16 + transpose ----------------
// w_upT [256][128], w_dT [3][256][256] (row = out col, contiguous = in/K), w_fT [16][256] (rows 12..15 zero)

__global__ void prep_kernel(const float* __restrict__ w_up, const float* __restrict__ w_dense,
                            const float* __restrict__ w_final,
                            short* __restrict__ w_upT, short* __restrict__ w_dT,
                            short* __restrict__ w_fT) {
    const int T1 = OUT * EMB;            // 32768
    const int T2 = NDL * OUT * OUT;      // 196608
    const int T3 = 16 * OUT;             // 4096
    int total = T1 + T2 + T3;
    for (int i = blockIdx.x * blockDim.x + threadIdx.x; i < total; i += gridDim.x * blockDim.x) {
        if (i < T1) {
            int n = i >> 7, k = i & 127;
            w_upT[i] = f2bf(w_up[k * OUT + n]);
        } else if (i < T1 + T2) {
            int j = i - T1;
            int l = j >> 16, o = (j >> 8) & 255, k = j & 255;
            w_dT[j] = f2bf(w_dense[(l << 16) + (k << 8) + o]);
        } else {
            int j = i - T1 - T2;
            int t = j >> 8, k = j & 255;
            w_fT[j] = (t < NTGT) ? f2bf(w_final[k * NTGT + t]) : (short)0;
        }
    }
}

// ---------------- edge gather: t0[n,:] = sum_e m[e,:] * (rbf[e,:] @ w_rbf), bf16 out ----------------

__global__ void gather_kernel(const float* __restrict__ m, const float* __restrict__ rbf,
                              const float* __restrict__ w_rbf,
                              const int* __restrict__ offs, const int* __restrict__ eids,
                              __hip_bfloat16* __restrict__ t0, int N) {
    int n = blockIdx.x;
    int tid = threadIdx.x;  // 128 threads, one per emb element
    float wr[RAD];
#pragma unroll
    for (int r = 0; r < RAD; r++) wr[r] = w_rbf[r * EMB + tid];

    int b = offs[n], e = offs[n + 1];
    float acc = 0.f;
    int idx = b;
    for (; idx + 4 <= e; idx += 4) {
        int e0 = eids[idx], e1 = eids[idx + 1], e2 = eids[idx + 2], e3 = eids[idx + 3];
        float c0 = 0.f, c1 = 0.f, c2 = 0.f, c3 = 0.f;
#pragma unroll
        for (int r = 0; r < RAD; r++) {
            c0 += rbf[(size_t)e0 * RAD + r] * wr[r];
            c1 += rbf[(size_t)e1 * RAD + r] * wr[r];
            c2 += rbf[(size_t)e2 * RAD + r] * wr[r];
            c3 += rbf[(size_t)e3 * RAD + r] * wr[r];
        }
        float m0 = m[(size_t)e0 * EMB + tid];
        float m1 = m[(size_t)e1 * EMB + tid];
        float m2 = m[(size_t)e2 * EMB + tid];
        float m3 = m[(size_t)e3 * EMB + tid];
        acc += m0 * c0 + m1 * c1 + m2 * c2 + m3 * c3;
    }
    for (; idx < e; idx++) {
        int e0 = eids[idx];
        float c0 = 0.f;
#pragma unroll
        for (int r = 0; r < RAD; r++) c0 += rbf[(size_t)e0 * RAD + r] * wr[r];
        acc += m[(size_t)e0 * EMB + tid] * c0;
    }
    t0[(size_t)n * EMB + tid] = __float2bfloat16(acc);
}

// ---------------- node MLP chain via MFMA + per-graph reduce ----------------
// 256 threads = 4 waves. Block tile: MT=32 nodes x 256 cols. Wave w owns cols [64w, 64w+64).
// Per wave per K-chunk(32): 2 A-frags (LDS), 4 B-frags (global/L2), 8 MFMAs.

__global__ __launch_bounds__(256) void chain_kernel(
    const __hip_bfloat16* __restrict__ t0,
    const short* __restrict__ w_upT, const short* __restrict__ w_dT,
    const float* __restrict__ b_dense, const short* __restrict__ w_fT,
    const int* __restrict__ node2graph, float* __restrict__ out, int N) {

    __shared__ short sA[2][MT * S];   // 2 x 16.9 KB bf16 activation buffers

    int tid = threadIdx.x;
    int n0 = blockIdx.x * MT;
    int wave = tid >> 6, lane = tid & 63;
    int lo = lane & 15;          // A row / B col / C col
    int quad = lane >> 4;
    int kq = quad * 8;
    int wcol = wave * 64;

    // ---- stage t0 tile (bf16, zero-fill past N) ----
    {
        int r = tid >> 3;             // 0..31
        int c = (tid & 7) * 16;       // 0..112 step 16
        uint4 v0 = {0, 0, 0, 0}, v1 = {0, 0, 0, 0};
        if (n0 + r < N) {
            const uint4* src = (const uint4*)((const short*)t0 + (size_t)(n0 + r) * EMB + c);
            v0 = src[0];
            v1 = src[1];
        }
        *(uint4*)&sA[0][r * S + c] = v0;
        *(uint4*)&sA[0][r * S + c + 8] = v1;
    }
    __syncthreads();

    // ---- generic layer: read sA[cur], write sA[cur^1] ----
    auto layer = [&](int cur, int K, const short* __restrict__ Bt,
                     const float* __restrict__ bias, bool act) {
        floatx4 acc[2][4];
#pragma unroll
        for (int mt = 0; mt < 2; mt++)
#pragma unroll
            for (int nt = 0; nt < 4; nt++)
                acc[mt][nt] = floatx4{0.f, 0.f, 0.f, 0.f};

        for (int kc = 0; kc < K; kc += 32) {
            short8 a0 = *(const short8*)&sA[cur][(lo) * S + kc + kq];
            short8 a1 = *(const short8*)&sA[cur][(16 + lo) * S + kc + kq];
#pragma unroll
            for (int nt = 0; nt < 4; nt++) {
                int n = wcol + nt * 16 + lo;
                short8 b = *(const short8*)&Bt[(size_t)n * K + kc + kq];
                acc[0][nt] = __builtin_amdgcn_mfma_f32_16x16x32_bf16(a0, b, acc[0][nt], 0, 0, 0);
                acc[1][nt] = __builtin_amdgcn_mfma_f32_16x16x32_bf16(a1, b, acc[1][nt], 0, 0, 0);
            }
        }

        float bv[4];
#pragma unroll
        for (int nt = 0; nt < 4; nt++) bv[nt] = bias ? bias[wcol + nt * 16 + lo] : 0.f;

        short* dst = sA[cur ^ 1];
#pragma unroll
        for (int mt = 0; mt < 2; mt++)
#pragma unroll
            for (int nt = 0; nt < 4; nt++) {
                int n = wcol + nt * 16 + lo;
#pragma unroll
                for (int i = 0; i < 4; i++) {
                    int mrow = mt * 16 + quad * 4 + i;
                    float x = acc[mt][nt][i] + bv[nt];
                    if (act) x = x / (1.f + __expf(-x));
                    dst[mrow * S + n] = f2bf(x);
                }
            }
        __syncthreads();
    };

    layer(0, EMB, w_upT, nullptr, false);                       // up:    buf0 -> buf1
    layer(1, OUT, w_dT + 0 * OUT * OUT, b_dense + 0 * OUT, true);   // d0: 1 -> 0
    layer(0, OUT, w_dT + 1 * OUT * OUT, b_dense + 1 * OUT, true);   // d1: 0 -> 1
    layer(1, OUT, w_dT + 2 * OUT * OUT, b_dense + 2 * OUT, true);   // d2: 1 -> 0

    // ---- final 256 -> 12 via MFMA (N padded to 16), wave 0 only ----
    if (wave == 0) {
        floatx4 facc[2];
        facc[0] = floatx4{0.f, 0.f, 0.f, 0.f};
        facc[1] = floatx4{0.f, 0.f, 0.f, 0.f};
        for (int kc = 0; kc < OUT; kc += 32) {
            short8 a0 = *(const short8*)&sA[0][(lo) * S + kc + kq];
            short8 a1 = *(const short8*)&sA[0][(16 + lo) * S + kc + kq];
            short8 b = *(const short8*)&w_fT[lo * OUT + kc + kq];
            facc[0] = __builtin_amdgcn_mfma_f32_16x16x32_bf16(a0, b, facc[0], 0, 0, 0);
            facc[1] = __builtin_amdgcn_mfma_f32_16x16x32_bf16(a1, b, facc[1], 0, 0, 0);
        }
        if (lo < NTGT) {
#pragma unroll
            for (int mt = 0; mt < 2; mt++)
#pragma unroll
                for (int i = 0; i < 4; i++) {
                    int node = n0 + mt * 16 + quad * 4 + i;
                    if (node < N)
                        atomicAdd(&out[node2graph[node] * NTGT + lo], facc[mt][i]);
                }
        }
    }
}

// ---------------- launch ----------------

extern "C" void kernel_launch(void* const* d_in, const int* in_sizes, int n_in,
                              void* d_out, int out_size, void* d_ws, size_t ws_size,
                              hipStream_t stream) {
    const float* m        = (const float*)d_in[0];
    const float* rbf      = (const float*)d_in[1];
    const int*   edge_src = (const int*)d_in[2];
    const int*   node2g   = (const int*)d_in[3];
    const float* w_rbf    = (const float*)d_in[4];
    const float* w_up     = (const float*)d_in[5];
    const float* w_dense  = (const float*)d_in[6];
    const float* b_dense  = (const float*)d_in[7];
    const float* w_final  = (const float*)d_in[8];

    int E = in_sizes[2];
    int N = in_sizes[3];
    float* out = (float*)d_out;

    char* p = (char*)d_ws;
    auto alloc = [&](size_t bytes) {
        char* r = p;
        p += (bytes + 255) & ~(size_t)255;
        return r;
    };
    int*   counts = (int*)alloc((size_t)N * 4);
    int*   offs   = (int*)alloc((size_t)(N + 1) * 4);
    int*   cursor = (int*)alloc((size_t)N * 4);
    int*   eids   = (int*)alloc((size_t)E * 4);
    __hip_bfloat16* t0 = (__hip_bfloat16*)alloc((size_t)N * EMB * 2);
    short* w_upT  = (short*)alloc((size_t)OUT * EMB * 2);
    short* w_dT   = (short*)alloc((size_t)NDL * OUT * OUT * 2);
    short* w_fT   = (short*)alloc((size_t)16 * OUT * 2);

    hipMemsetAsync(counts, 0, (size_t)N * 4, stream);
    hipMemsetAsync(d_out, 0, (size_t)out_size * 4, stream);

    prep_kernel<<<512, 256, 0, stream>>>(w_up, w_dense, w_final, w_upT, w_dT, w_fT);
    hist_kernel<<<(E + 255) / 256, 256, 0, stream>>>(edge_src, counts, E);
    scan_kernel<<<1, 1024, 0, stream>>>(counts, offs, cursor, N);
    scatter_kernel<<<(E + 255) / 256, 256, 0, stream>>>(edge_src, cursor, eids, E);
    gather_kernel<<<N, EMB, 0, stream>>>(m, rbf, w_rbf, offs, eids, t0, N);
    chain_kernel<<<(N + MT - 1) / MT, 256, 0, stream>>>(t0, w_upT, w_dT, b_dense,
                                                        w_fT, node2g, out, N);
}

// Round 3
// 764.254 us; speedup vs baseline: 1.3192x; 1.0125x over previous
//
#include <hip/hip_runtime.h>
#include <hip/hip_bf16.h>
#include <math.h>

#define EMB 128
#define OUT 256
#define RAD 6
#define NDL 3
#define NTGT 12
#define MT 32          // nodes per chain block
#define S 264          // LDS activation stride (bf16 elems)
#define ECH 1024       // gather: eids staged per chunk

typedef __attribute__((ext_vector_type(8))) short short8;
typedef __attribute__((ext_vector_type(4))) float floatx4;

__device__ inline short f2bf(float x) {
    __hip_bfloat16 h = __float2bfloat16(x);
    return *reinterpret_cast<short*>(&h);
}

// ---------------- CSR build ----------------

__global__ void hist_kernel(const int* __restrict__ src, int* __restrict__ counts, int E) {
    int i = blockIdx.x * blockDim.x + threadIdx.x;
    if (i < E) atomicAdd(&counts[src[i]], 1);
}

__global__ void scan_kernel(const int* __restrict__ counts, int* __restrict__ offs,
                            int* __restrict__ cursor, int N) {
    __shared__ int sums[1024];
    int tid = threadIdx.x;
    int chunk = (N + 1023) / 1024;
    int beg = tid * chunk;
    int end = min(beg + chunk, N);
    int s = 0;
    for (int i = beg; i < end; i++) s += counts[i];
    int mysum = s;
    sums[tid] = s;
    __syncthreads();
    for (int off = 1; off < 1024; off <<= 1) {
        int add = (tid >= off) ? sums[tid - off] : 0;
        __syncthreads();
        sums[tid] += add;
        __syncthreads();
    }
    int prefix = sums[tid] - mysum;
    for (int i = beg; i < end; i++) {
        int c = counts[i];
        offs[i] = prefix;
        cursor[i] = prefix;
        prefix += c;
    }
    if (tid == 0) offs[N] = sums[1023];
}

__global__ void scatter_kernel(const int* __restrict__ src, int* __restrict__ cursor,
                               int* __restrict__ eids, int E) {
    int i = blockIdx.x * blockDim.x + threadIdx.x;
    if (i < E) {
        int pos = atomicAdd(&cursor[src[i]], 1);
        eids[pos] = i;
    }
}

// ---------------- weight prep: bf16 + transpose ----------------

__global__ void prep_kernel(const float* __restrict__ w_up, const float* __restrict__ w_dense,
                            const float* __restrict__ w_final,
                            short* __restrict__ w_upT, short* __restrict__ w_dT,
                            short* __restrict__ w_fT) {
    const int T1 = OUT * EMB;
    const int T2 = NDL * OUT * OUT;
    const int T3 = 16 * OUT;
    int total = T1 + T2 + T3;
    for (int i = blockIdx.x * blockDim.x + threadIdx.x; i < total; i += gridDim.x * blockDim.x) {
        if (i < T1) {
            int n = i >> 7, k = i & 127;
            w_upT[i] = f2bf(w_up[k * OUT + n]);
        } else if (i < T1 + T2) {
            int j = i - T1;
            int l = j >> 16, o = (j >> 8) & 255, k = j & 255;
            w_dT[j] = f2bf(w_dense[(l << 16) + (k << 8) + o]);
        } else {
            int j = i - T1 - T2;
            int t = j >> 8, k = j & 255;
            w_fT[j] = (t < NTGT) ? f2bf(w_final[k * NTGT + t]) : (short)0;
        }
    }
}

// ---------------- edge gather ----------------
// 128 threads = 4 edge-groups x 32 col-lanes. Lane covers cols 4c..4c+3 (float4 m loads).
// eids staged to LDS per chunk; w_rbf preloaded as 6 float4; unroll-2 (8 edges in flight).

__global__ __launch_bounds__(128) void gather_kernel(
    const float* __restrict__ m, const float* __restrict__ rbf,
    const float* __restrict__ w_rbf,
    const int* __restrict__ offs, const int* __restrict__ eids,
    __hip_bfloat16* __restrict__ t0, int N) {

    __shared__ int sEid[ECH];
    __shared__ float sRed[32 * 4];

    int n = blockIdx.x;
    int tid = threadIdx.x;
    int grp = tid >> 5;       // 0..3 edge group
    int c = tid & 31;         // column group -> cols 4c..4c+3

    float4 wq[RAD];
#pragma unroll
    for (int r = 0; r < RAD; r++) wq[r] = *(const float4*)&w_rbf[r * EMB + 4 * c];

    int b = offs[n], e = offs[n + 1];
    float ax = 0.f, ay = 0.f, az = 0.f, aw = 0.f;

    for (int base = b; base < e; base += ECH) {
        int cnt = min(ECH, e - base);
        __syncthreads();
        for (int i = tid; i < cnt; i += 128) sEid[i] = eids[base + i];
        __syncthreads();

        int i = grp;
        for (; i + 8 <= cnt; i += 8) {
            int e0 = sEid[i], e1 = sEid[i + 4];
            const float* rb0 = &rbf[(size_t)e0 * RAD];
            const float* rb1 = &rbf[(size_t)e1 * RAD];
            float2 p0 = *(const float2*)&rb0[0];
            float2 p1 = *(const float2*)&rb0[2];
            float2 p2 = *(const float2*)&rb0[4];
            float2 q0 = *(const float2*)&rb1[0];
            float2 q1 = *(const float2*)&rb1[2];
            float2 q2 = *(const float2*)&rb1[4];
            float4 m0 = *(const float4*)&m[(size_t)e0 * EMB + 4 * c];
            float4 m1 = *(const float4*)&m[(size_t)e1 * EMB + 4 * c];

            float cx0 = wq[0].x * p0.x + wq[1].x * p0.y + wq[2].x * p1.x + wq[3].x * p1.y + wq[4].x * p2.x + wq[5].x * p2.y;
            float cy0 = wq[0].y * p0.x + wq[1].y * p0.y + wq[2].y * p1.x + wq[3].y * p1.y + wq[4].y * p2.x + wq[5].y * p2.y;
            float cz0 = wq[0].z * p0.x + wq[1].z * p0.y + wq[2].z * p1.x + wq[3].z * p1.y + wq[4].z * p2.x + wq[5].z * p2.y;
            float cw0 = wq[0].w * p0.x + wq[1].w * p0.y + wq[2].w * p1.x + wq[3].w * p1.y + wq[4].w * p2.x + wq[5].w * p2.y;
            ax += m0.x * cx0; ay += m0.y * cy0; az += m0.z * cz0; aw += m0.w * cw0;

            float cx1 = wq[0].x * q0.x + wq[1].x * q0.y + wq[2].x * q1.x + wq[3].x * q1.y + wq[4].x * q2.x + wq[5].x * q2.y;
            float cy1 = wq[0].y * q0.x + wq[1].y * q0.y + wq[2].y * q1.x + wq[3].y * q1.y + wq[4].y * q2.x + wq[5].y * q2.y;
            float cz1 = wq[0].z * q0.x + wq[1].z * q0.y + wq[2].z * q1.x + wq[3].z * q1.y + wq[4].z * q2.x + wq[5].z * q2.y;
            float cw1 = wq[0].w * q0.x + wq[1].w * q0.y + wq[2].w * q1.x + wq[3].w * q1.y + wq[4].w * q2.x + wq[5].w * q2.y;
            ax += m1.x * cx1; ay += m1.y * cy1; az += m1.z * cz1; aw += m1.w * cw1;
        }
        for (; i < cnt; i += 4) {
            int e0 = sEid[i];
            const float* rb0 = &rbf[(size_t)e0 * RAD];
            float2 p0 = *(const float2*)&rb0[0];
            float2 p1 = *(const float2*)&rb0[2];
            float2 p2 = *(const float2*)&rb0[4];
            float4 m0 = *(const float4*)&m[(size_t)e0 * EMB + 4 * c];
            float cx0 = wq[0].x * p0.x + wq[1].x * p0.y + wq[2].x * p1.x + wq[3].x * p1.y + wq[4].x * p2.x + wq[5].x * p2.y;
            float cy0 = wq[0].y * p0.x + wq[1].y * p0.y + wq[2].y * p1.x + wq[3].y * p1.y + wq[4].y * p2.x + wq[5].y * p2.y;
            float cz0 = wq[0].z * p0.x + wq[1].z * p0.y + wq[2].z * p1.x + wq[3].z * p1.y + wq[4].z * p2.x + wq[5].z * p2.y;
            float cw0 = wq[0].w * p0.x + wq[1].w * p0.y + wq[2].w * p1.x + wq[3].w * p1.y + wq[4].w * p2.x + wq[5].w * p2.y;
            ax += m0.x * cx0; ay += m0.y * cy0; az += m0.z * cz0; aw += m0.w * cw0;
        }
    }

    // reduce across the 4 edge groups: intra-wave (grp pairs 0/1 and 2/3) via xor-32
    ax += __shfl_xor(ax, 32); ay += __shfl_xor(ay, 32);
    az += __shfl_xor(az, 32); aw += __shfl_xor(aw, 32);
    // inter-wave via LDS
    __syncthreads();
    if (tid >= 64 && tid < 96) {
        sRed[c * 4 + 0] = ax; sRed[c * 4 + 1] = ay;
        sRed[c * 4 + 2] = az; sRed[c * 4 + 3] = aw;
    }
    __syncthreads();
    if (tid < 32) {
        ax += sRed[c * 4 + 0]; ay += sRed[c * 4 + 1];
        az += sRed[c * 4 + 2]; aw += sRed[c * 4 + 3];
        __hip_bfloat16* dst = t0 + (size_t)n * EMB + 4 * c;
        dst[0] = __float2bfloat16(ax);
        dst[1] = __float2bfloat16(ay);
        dst[2] = __float2bfloat16(az);
        dst[3] = __float2bfloat16(aw);
    }
}

// ---------------- node MLP chain via MFMA + per-graph reduce ----------------

__global__ __launch_bounds__(256) void chain_kernel(
    const __hip_bfloat16* __restrict__ t0,
    const short* __restrict__ w_upT, const short* __restrict__ w_dT,
    const float* __restrict__ b_dense, const short* __restrict__ w_fT,
    const int* __restrict__ node2graph, float* __restrict__ out, int N) {

    __shared__ short sA[2][MT * S];

    int tid = threadIdx.x;
    int n0 = blockIdx.x * MT;
    int wave = tid >> 6, lane = tid & 63;
    int lo = lane & 15;
    int quad = lane >> 4;
    int kq = quad * 8;
    int wcol = wave * 64;

    {
        int r = tid >> 3;
        int c = (tid & 7) * 16;
        uint4 v0 = {0, 0, 0, 0}, v1 = {0, 0, 0, 0};
        if (n0 + r < N) {
            const uint4* src = (const uint4*)((const short*)t0 + (size_t)(n0 + r) * EMB + c);
            v0 = src[0];
            v1 = src[1];
        }
        *(uint4*)&sA[0][r * S + c] = v0;
        *(uint4*)&sA[0][r * S + c + 8] = v1;
    }
    __syncthreads();

    auto layer = [&](int cur, int K, const short* __restrict__ Bt,
                     const float* __restrict__ bias, bool act) {
        floatx4 acc[2][4];
#pragma unroll
        for (int mt = 0; mt < 2; mt++)
#pragma unroll
            for (int nt = 0; nt < 4; nt++)
                acc[mt][nt] = floatx4{0.f, 0.f, 0.f, 0.f};

        for (int kc = 0; kc < K; kc += 32) {
            short8 a0 = *(const short8*)&sA[cur][(lo) * S + kc + kq];
            short8 a1 = *(const short8*)&sA[cur][(16 + lo) * S + kc + kq];
#pragma unroll
            for (int nt = 0; nt < 4; nt++) {
                int n = wcol + nt * 16 + lo;
                short8 b = *(const short8*)&Bt[(size_t)n * K + kc + kq];
                acc[0][nt] = __builtin_amdgcn_mfma_f32_16x16x32_bf16(a0, b, acc[0][nt], 0, 0, 0);
                acc[1][nt] = __builtin_amdgcn_mfma_f32_16x16x32_bf16(a1, b, acc[1][nt], 0, 0, 0);
            }
        }

        float bv[4];
#pragma unroll
        for (int nt = 0; nt < 4; nt++) bv[nt] = bias ? bias[wcol + nt * 16 + lo] : 0.f;

        short* dst = sA[cur ^ 1];
#pragma unroll
        for (int mt = 0; mt < 2; mt++)
#pragma unroll
            for (int nt = 0; nt < 4; nt++) {
                int n = wcol + nt * 16 + lo;
#pragma unroll
                for (int i = 0; i < 4; i++) {
                    int mrow = mt * 16 + quad * 4 + i;
                    float x = acc[mt][nt][i] + bv[nt];
                    if (act) x = x / (1.f + __expf(-x));
                    dst[mrow * S + n] = f2bf(x);
                }
            }
        __syncthreads();
    };

    layer(0, EMB, w_upT, nullptr, false);
    layer(1, OUT, w_dT + 0 * OUT * OUT, b_dense + 0 * OUT, true);
    layer(0, OUT, w_dT + 1 * OUT * OUT, b_dense + 1 * OUT, true);
    layer(1, OUT, w_dT + 2 * OUT * OUT, b_dense + 2 * OUT, true);

    if (wave == 0) {
        floatx4 facc[2];
        facc[0] = floatx4{0.f, 0.f, 0.f, 0.f};
        facc[1] = floatx4{0.f, 0.f, 0.f, 0.f};
        for (int kc = 0; kc < OUT; kc += 32) {
            short8 a0 = *(const short8*)&sA[0][(lo) * S + kc + kq];
            short8 a1 = *(const short8*)&sA[0][(16 + lo) * S + kc + kq];
            short8 b = *(const short8*)&w_fT[lo * OUT + kc + kq];
            facc[0] = __builtin_amdgcn_mfma_f32_16x16x32_bf16(a0, b, facc[0], 0, 0, 0);
            facc[1] = __builtin_amdgcn_mfma_f32_16x16x32_bf16(a1, b, facc[1], 0, 0, 0);
        }
        if (lo < NTGT) {
#pragma unroll
            for (int mt = 0; mt < 2; mt++)
#pragma unroll
                for (int i = 0; i < 4; i++) {
                    int node = n0 + mt * 16 + quad * 4 + i;
                    if (node < N)
                        atomicAdd(&out[node2graph[node] * NTGT + lo], facc[mt][i]);
                }
        }
    }
}

// ---------------- launch ----------------

extern "C" void kernel_launch(void* const* d_in, const int* in_sizes, int n_in,
                              void* d_out, int out_size, void* d_ws, size_t ws_size,
                              hipStream_t stream) {
    const float* m        = (const float*)d_in[0];
    const float* rbf      = (const float*)d_in[1];
    const int*   edge_src = (const int*)d_in[2];
    const int*   node2g   = (const int*)d_in[3];
    const float* w_rbf    = (const float*)d_in[4];
    const float* w_up     = (const float*)d_in[5];
    const float* w_dense  = (const float*)d_in[6];
    const float* b_dense  = (const float*)d_in[7];
    const float* w_final  = (const float*)d_in[8];

    int E = in_sizes[2];
    int N = in_sizes[3];
    float* out = (float*)d_out;

    char* p = (char*)d_ws;
    auto alloc = [&](size_t bytes) {
        char* r = p;
        p += (bytes + 255) & ~(size_t)255;
        return r;
    };
    int*   counts = (int*)alloc((size_t)N * 4);
    int*   offs   = (int*)alloc((size_t)(N + 1) * 4);
    int*   cursor = (int*)alloc((size_t)N * 4);
    int*   eids   = (int*)alloc((size_t)E * 4);
    __hip_bfloat16* t0 = (__hip_bfloat16*)alloc((size_t)N * EMB * 2);
    short* w_upT  = (short*)alloc((size_t)OUT * EMB * 2);
    short* w_dT   = (short*)alloc((size_t)NDL * OUT * OUT * 2);
    short* w_fT   = (short*)alloc((size_t)16 * OUT * 2);

    hipMemsetAsync(counts, 0, (size_t)N * 4, stream);
    hipMemsetAsync(d_out, 0, (size_t)out_size * 4, stream);

    prep_kernel<<<512, 256, 0, stream>>>(w_up, w_dense, w_final, w_upT, w_dT, w_fT);
    hist_kernel<<<(E + 255) / 256, 256, 0, stream>>>(edge_src, counts, E);
    scan_kernel<<<1, 1024, 0, stream>>>(counts, offs, cursor, N);
    scatter_kernel<<<(E + 255) / 256, 256, 0, stream>>>(edge_src, cursor, eids, E);
    gather_kernel<<<N, 128, 0, stream>>>(m, rbf, w_rbf, offs, eids, t0, N);
    chain_kernel<<<(N + MT - 1) / MT, 256, 0, stream>>>(t0, w_upT, w_dT, b_dense,
                                                        w_fT, node2g, out, N);
}